// Round 2
// baseline (144.040 us; speedup 1.0000x reference)
//
#include <hip/hip_runtime.h>

#define NROWS 2048
#define KDIM  768
#define L     40
#define KCH   6          // K-chunks per matrix (768 = 6 * 128)
#define KCSZ  128        // K per chunk
#define HN    (NROWS * L)   // 81920 floats per h matrix

// ---------------------------------------------------------------------------
// Kernel 1: partial projections with K split across blocks (proven 116µs path).
//   part[(kc*2+which)*HN + row*L + o] = sum_{k in chunk kc} A[row][k]*W1[o][k']
// grid (128 rowblocks, 6 kchunks, 2 matrices), block 256 = 16 rows x 16 segs.
// ---------------------------------------------------------------------------
__global__ __launch_bounds__(256) void k_proj(const float* __restrict__ x,
                                              const float* __restrict__ y,
                                              const float* __restrict__ W1,
                                              float* __restrict__ part) {
    const int kc    = blockIdx.y;
    const int which = blockIdx.z;
    const float* __restrict__ A = which ? y : x;
    const int tid = threadIdx.x;
    const int r   = tid >> 4;    // 0..15 row within block
    const int seg = tid & 15;    // 0..15 K-segment (8 floats each)
    const int row0 = blockIdx.x * 16;

    // partials: [16 rows][40 o][16 segs], row stride 688
    __shared__ float sh[16 * 688];

    const float* arow = A + (size_t)(row0 + r) * KDIM + kc * KCSZ;
    float4 a0 = *(const float4*)(arow + seg * 4);
    float4 a1 = *(const float4*)(arow + 64 + seg * 4);

    const float* wbase = W1 + (size_t)which * KDIM + kc * KCSZ;
#pragma unroll 8
    for (int o = 0; o < L; ++o) {
        const float* wrow = wbase + (size_t)o * (2 * KDIM);
        float4 w0 = *(const float4*)(wrow + seg * 4);
        float4 w1 = *(const float4*)(wrow + 64 + seg * 4);
        float s = a0.x * w0.x + a0.y * w0.y + a0.z * w0.z + a0.w * w0.w
                + a1.x * w1.x + a1.y * w1.y + a1.z * w1.z + a1.w * w1.w;
        sh[r * 688 + o * 17 + seg] = s;
    }
    __syncthreads();

    float* pout = part + (size_t)(kc * 2 + which) * HN + (size_t)row0 * L;
    for (int idx = tid; idx < 16 * L; idx += 256) {
        int rr = idx / L;
        int o  = idx - rr * L;
        float s = 0.f;
        int base = rr * 688 + o * 17;
#pragma unroll
        for (int q = 0; q < 16; ++q) s += sh[base + q];
        pout[idx] = s;
    }
}

// ---------------------------------------------------------------------------
// Kernel 1b: reduce the 6 K-chunk partials -> hxb (b1 folded in) and hy.
// Also zeroes the sums/counter slots (replaces the memset dispatch).
// ---------------------------------------------------------------------------
__global__ __launch_bounds__(256) void k_red(const float* __restrict__ part,
                                             const float* __restrict__ b1,
                                             float* __restrict__ hxb,
                                             float* __restrict__ hy,
                                             float* __restrict__ sums) {
    if (blockIdx.x == 0 && threadIdx.x < 4) sums[threadIdx.x] = 0.f;
    int gid = blockIdx.x * 256 + threadIdx.x;   // 0 .. 2*HN-1
    int which = gid / HN;
    int rem   = gid - which * HN;
    float s = 0.f;
#pragma unroll
    for (int kc = 0; kc < KCH; ++kc)
        s += part[(size_t)(kc * 2 + which) * HN + rem];
    if (!which) {
        s += b1[rem % L];
        hxb[rem] = s;
    } else {
        hy[rem] = s;
    }
}

// ---------------------------------------------------------------------------
// Kernel 2: pairwise sum of exp(T_ij - 1) + diagonal T0 sum.
// Tile: BI=64 (i) x BJ=64 (j), grid 32x32 = 1024 blocks -> 4 blocks/CU
// (16 waves/CU, 4 waves/SIMD — double the latency hiding of the 128x64 version).
// block 256 = 16(ty,i) x 16(tx,j), micro-tile 4x4 lane-interleaved.
// __launch_bounds__(256,4): cap 128 VGPR — room for deep LDS-read pipelining.
// Last block to finish computes the final scalar (k_fin fused).
// ---------------------------------------------------------------------------
#define BI 64
#define BJ 64
#define STRD 44

__global__ __launch_bounds__(256, 4) void k_pair(const float* __restrict__ hxb,
                                                 const float* __restrict__ hy,
                                                 const float* __restrict__ W2,
                                                 const float* __restrict__ b2p,
                                                 float* __restrict__ sums,
                                                 float* __restrict__ out) {
    __shared__ float shy[BI * STRD];
    __shared__ float shx[BJ * STRD];
    __shared__ float sw2[STRD];
    __shared__ float red[8];

    const int tid = threadIdx.x;
    const int i0 = blockIdx.x * BI;
    const int j0 = blockIdx.y * BJ;

    for (int idx = tid; idx < BI * 10; idx += 256) {
        int rr = idx / 10, c = idx - rr * 10;
        float4 v = ((const float4*)(hy + (size_t)i0 * L))[idx];
        *(float4*)(shy + rr * STRD + c * 4) = v;
    }
    for (int idx = tid; idx < BJ * 10; idx += 256) {
        int rr = idx / 10, c = idx - rr * 10;
        float4 v = ((const float4*)(hxb + (size_t)j0 * L))[idx];
        *(float4*)(shx + rr * STRD + c * 4) = v;
    }
    if (tid < 10) ((float4*)sw2)[tid] = ((const float4*)W2)[tid];
    __syncthreads();

    const int tx = tid & 15, ty = tid >> 4;

    float acc[4][4];
#pragma unroll
    for (int u = 0; u < 4; ++u)
#pragma unroll
        for (int v = 0; v < 4; ++v) acc[u][v] = 0.f;

#pragma unroll
    for (int k4 = 0; k4 < 10; ++k4) {
        float4 w = *(const float4*)(sw2 + k4 * 4);
        float4 ay[4], ax[4];
#pragma unroll
        for (int u = 0; u < 4; ++u)
            ay[u] = *(const float4*)(shy + (ty + 16 * u) * STRD + k4 * 4);
#pragma unroll
        for (int v = 0; v < 4; ++v)
            ax[v] = *(const float4*)(shx + (tx + 16 * v) * STRD + k4 * 4);
#pragma unroll
        for (int u = 0; u < 4; ++u)
#pragma unroll
            for (int v = 0; v < 4; ++v) {
                float t;
                t = ay[u].x + ax[v].x; t = fmaxf(t, 0.f); acc[u][v] += t * w.x;
                t = ay[u].y + ax[v].y; t = fmaxf(t, 0.f); acc[u][v] += t * w.y;
                t = ay[u].z + ax[v].z; t = fmaxf(t, 0.f); acc[u][v] += t * w.z;
                t = ay[u].w + ax[v].w; t = fmaxf(t, 0.f); acc[u][v] += t * w.w;
            }
    }

    const float b2v = b2p[0];
    const float c1  = b2v - 1.f;
    float sumE = 0.f, sumT = 0.f;
#pragma unroll
    for (int u = 0; u < 4; ++u)
#pragma unroll
        for (int v = 0; v < 4; ++v) {
            int gi = i0 + ty + 16 * u;
            int gj = j0 + tx + 16 * v;
            float val = acc[u][v];
            if (gi == gj) sumT += val + b2v;
            sumE += __expf(val + c1);
        }

#pragma unroll
    for (int off = 32; off > 0; off >>= 1) {
        sumE += __shfl_down(sumE, off);
        sumT += __shfl_down(sumT, off);
    }
    int wid = tid >> 6;
    if ((tid & 63) == 0) { red[wid] = sumE; red[4 + wid] = sumT; }
    __syncthreads();
    if (tid == 0) {
        float e = red[0] + red[1] + red[2] + red[3];
        float t = red[4] + red[5] + red[6] + red[7];
        atomicAdd(&sums[1], e);
        atomicAdd(&sums[0], t);
        __threadfence();
        unsigned total = gridDim.x * gridDim.y;
        unsigned prev = __hip_atomic_fetch_add((unsigned*)(sums + 2), 1u,
                                               __ATOMIC_ACQ_REL,
                                               __HIP_MEMORY_SCOPE_AGENT);
        if (prev == total - 1) {
            float st = __hip_atomic_load(sums + 0, __ATOMIC_RELAXED,
                                         __HIP_MEMORY_SCOPE_AGENT);
            float se = __hip_atomic_load(sums + 1, __ATOMIC_RELAXED,
                                         __HIP_MEMORY_SCOPE_AGENT);
            const float invN = 1.0f / (float)NROWS;
            out[0] = st * invN - se * invN * invN;
        }
    }
}

extern "C" void kernel_launch(void* const* d_in, const int* in_sizes, int n_in,
                              void* d_out, int out_size, void* d_ws, size_t ws_size,
                              hipStream_t stream) {
    const float* x  = (const float*)d_in[0];
    const float* y  = (const float*)d_in[1];
    const float* W1 = (const float*)d_in[2];
    const float* b1 = (const float*)d_in[3];
    const float* W2 = (const float*)d_in[4];
    const float* b2 = (const float*)d_in[5];
    float* out = (float*)d_out;

    float* wsf  = (float*)d_ws;
    float* sums = wsf;                   // [0]=sumT0, [1]=sumExp, [2]=block counter
    float* hxb  = wsf + 16;              // 2048*40, b1 folded in
    float* hy   = hxb + HN;              // 2048*40
    float* part = hy + HN;               // 6*2*2048*40 partials

    k_proj<<<dim3(NROWS / 16, KCH, 2), 256, 0, stream>>>(x, y, W1, part);
    k_red<<<(2 * HN) / 256, 256, 0, stream>>>(part, b1, hxb, hy, sums);
    k_pair<<<dim3(NROWS / BI, NROWS / BJ), 256, 0, stream>>>(hxb, hy, W2, b2, sums, out);
}

// Round 3
// 99.994 us; speedup vs baseline: 1.4405x; 1.4405x over previous
//
#include <hip/hip_runtime.h>

#define NROWS 2048
#define KDIM  768
#define L     40
#define KCH   6          // K-chunks per matrix (768 = 6 * 128)
#define KCSZ  128        // K per chunk
#define HN    (NROWS * L)   // 81920 floats per h matrix

// ---------------------------------------------------------------------------
// Kernel 1: partial projections with K split across blocks (proven path).
// grid (128 rowblocks, 6 kchunks, 2 matrices), block 256 = 16 rows x 16 segs.
// ---------------------------------------------------------------------------
__global__ __launch_bounds__(256) void k_proj(const float* __restrict__ x,
                                              const float* __restrict__ y,
                                              const float* __restrict__ W1,
                                              float* __restrict__ part) {
    const int kc    = blockIdx.y;
    const int which = blockIdx.z;
    const float* __restrict__ A = which ? y : x;
    const int tid = threadIdx.x;
    const int r   = tid >> 4;
    const int seg = tid & 15;
    const int row0 = blockIdx.x * 16;

    __shared__ float sh[16 * 688];

    const float* arow = A + (size_t)(row0 + r) * KDIM + kc * KCSZ;
    float4 a0 = *(const float4*)(arow + seg * 4);
    float4 a1 = *(const float4*)(arow + 64 + seg * 4);

    const float* wbase = W1 + (size_t)which * KDIM + kc * KCSZ;
#pragma unroll 8
    for (int o = 0; o < L; ++o) {
        const float* wrow = wbase + (size_t)o * (2 * KDIM);
        float4 w0 = *(const float4*)(wrow + seg * 4);
        float4 w1 = *(const float4*)(wrow + 64 + seg * 4);
        float s = a0.x * w0.x + a0.y * w0.y + a0.z * w0.z + a0.w * w0.w
                + a1.x * w1.x + a1.y * w1.y + a1.z * w1.z + a1.w * w1.w;
        sh[r * 688 + o * 17 + seg] = s;
    }
    __syncthreads();

    float* pout = part + (size_t)(kc * 2 + which) * HN + (size_t)row0 * L;
    for (int idx = tid; idx < 16 * L; idx += 256) {
        int rr = idx / L;
        int o  = idx - rr * L;
        float s = 0.f;
        int base = rr * 688 + o * 17;
#pragma unroll
        for (int q = 0; q < 16; ++q) s += sh[base + q];
        pout[idx] = s;
    }
}

// ---------------------------------------------------------------------------
// Kernel 1b: reduce the 6 K-chunk partials -> hxb (b1 folded in) and hy.
// ---------------------------------------------------------------------------
__global__ __launch_bounds__(256) void k_red(const float* __restrict__ part,
                                             const float* __restrict__ b1,
                                             float* __restrict__ hxb,
                                             float* __restrict__ hy) {
    int gid = blockIdx.x * 256 + threadIdx.x;   // 0 .. 2*HN-1
    int which = gid / HN;
    int rem   = gid - which * HN;
    float s = 0.f;
#pragma unroll
    for (int kc = 0; kc < KCH; ++kc)
        s += part[(size_t)(kc * 2 + which) * HN + rem];
    if (!which) {
        s += b1[rem % L];
        hxb[rem] = s;
    } else {
        hy[rem] = s;
    }
}

// ---------------------------------------------------------------------------
// Kernel 2: pairwise sum of exp(T_ij - 1) + diagonal T0 sum.
// Tile BI=128 x BJ=64, block 512 = 32(ty,i) x 16(tx,j), micro-tile 4x4.
// 512 blocks x 8 waves -> 2 blocks/CU = 16 waves/CU = 4 waves/SIMD.
// NO atomics: per-block partials written to pairE/pairT (distinct addresses).
// (R1/R2 evidence: same-address atomic chains cost ~40ns/op serialized;
//  1024-deep chains were 41us of near-empty tail.)
// ---------------------------------------------------------------------------
#define BI 128
#define BJ 64
#define STRD 44

__global__ __launch_bounds__(512) void k_pair(const float* __restrict__ hxb,
                                              const float* __restrict__ hy,
                                              const float* __restrict__ W2,
                                              const float* __restrict__ b2p,
                                              float* __restrict__ pairE,
                                              float* __restrict__ pairT) {
    __shared__ float shy[BI * STRD];
    __shared__ float shx[BJ * STRD];
    __shared__ float sw2[STRD];
    __shared__ float red[16];

    const int tid = threadIdx.x;
    const int i0 = blockIdx.x * BI;
    const int j0 = blockIdx.y * BJ;

    for (int idx = tid; idx < BI * 10; idx += 512) {
        int rr = idx / 10, c = idx - rr * 10;
        float4 v = ((const float4*)(hy + (size_t)i0 * L))[idx];
        *(float4*)(shy + rr * STRD + c * 4) = v;
    }
    for (int idx = tid; idx < BJ * 10; idx += 512) {
        int rr = idx / 10, c = idx - rr * 10;
        float4 v = ((const float4*)(hxb + (size_t)j0 * L))[idx];
        *(float4*)(shx + rr * STRD + c * 4) = v;
    }
    if (tid < 10) ((float4*)sw2)[tid] = ((const float4*)W2)[tid];
    __syncthreads();

    const int tx = tid & 15, ty = tid >> 4;   // ty 0..31

    float acc[4][4];
#pragma unroll
    for (int u = 0; u < 4; ++u)
#pragma unroll
        for (int v = 0; v < 4; ++v) acc[u][v] = 0.f;

#pragma unroll
    for (int k4 = 0; k4 < 10; ++k4) {
        float4 w = *(const float4*)(sw2 + k4 * 4);
        float4 ay[4], ax[4];
#pragma unroll
        for (int u = 0; u < 4; ++u)
            ay[u] = *(const float4*)(shy + (ty + 32 * u) * STRD + k4 * 4);
#pragma unroll
        for (int v = 0; v < 4; ++v)
            ax[v] = *(const float4*)(shx + (tx + 16 * v) * STRD + k4 * 4);
#pragma unroll
        for (int u = 0; u < 4; ++u)
#pragma unroll
            for (int v = 0; v < 4; ++v) {
                float t;
                t = ay[u].x + ax[v].x; t = fmaxf(t, 0.f); acc[u][v] += t * w.x;
                t = ay[u].y + ax[v].y; t = fmaxf(t, 0.f); acc[u][v] += t * w.y;
                t = ay[u].z + ax[v].z; t = fmaxf(t, 0.f); acc[u][v] += t * w.z;
                t = ay[u].w + ax[v].w; t = fmaxf(t, 0.f); acc[u][v] += t * w.w;
            }
    }

    const float b2v = b2p[0];
    const float c1  = b2v - 1.f;
    float sumE = 0.f, sumT = 0.f;
#pragma unroll
    for (int u = 0; u < 4; ++u)
#pragma unroll
        for (int v = 0; v < 4; ++v) {
            int gi = i0 + ty + 32 * u;
            int gj = j0 + tx + 16 * v;
            float val = acc[u][v];
            if (gi == gj) sumT += val + b2v;
            sumE += __expf(val + c1);
        }

#pragma unroll
    for (int off = 32; off > 0; off >>= 1) {
        sumE += __shfl_down(sumE, off);
        sumT += __shfl_down(sumT, off);
    }
    int wid = tid >> 6;                     // 0..7
    if ((tid & 63) == 0) { red[wid] = sumE; red[8 + wid] = sumT; }
    __syncthreads();
    if (tid == 0) {
        float e = 0.f, t = 0.f;
#pragma unroll
        for (int q = 0; q < 8; ++q) { e += red[q]; t += red[8 + q]; }
        int bid = blockIdx.y * gridDim.x + blockIdx.x;   // 0..511
        pairE[bid] = e;
        pairT[bid] = t;
    }
}

// ---------------------------------------------------------------------------
// Kernel 3: reduce 512 block-partials -> lower_bound.
// ---------------------------------------------------------------------------
__global__ __launch_bounds__(512) void k_fin(const float* __restrict__ pairE,
                                             const float* __restrict__ pairT,
                                             float* __restrict__ out) {
    __shared__ float red[16];
    const int tid = threadIdx.x;
    float e = pairE[tid];
    float t = pairT[tid];
#pragma unroll
    for (int off = 32; off > 0; off >>= 1) {
        e += __shfl_down(e, off);
        t += __shfl_down(t, off);
    }
    int wid = tid >> 6;
    if ((tid & 63) == 0) { red[wid] = e; red[8 + wid] = t; }
    __syncthreads();
    if (tid == 0) {
        float se = 0.f, st = 0.f;
#pragma unroll
        for (int q = 0; q < 8; ++q) { se += red[q]; st += red[8 + q]; }
        const float invN = 1.0f / (float)NROWS;
        out[0] = st * invN - se * invN * invN;
    }
}

extern "C" void kernel_launch(void* const* d_in, const int* in_sizes, int n_in,
                              void* d_out, int out_size, void* d_ws, size_t ws_size,
                              hipStream_t stream) {
    const float* x  = (const float*)d_in[0];
    const float* y  = (const float*)d_in[1];
    const float* W1 = (const float*)d_in[2];
    const float* b1 = (const float*)d_in[3];
    const float* W2 = (const float*)d_in[4];
    const float* b2 = (const float*)d_in[5];
    float* out = (float*)d_out;

    float* wsf   = (float*)d_ws;
    float* hxb   = wsf;                  // 2048*40, b1 folded in
    float* hy    = hxb + HN;             // 2048*40
    float* part  = hy + HN;              // 6*2*2048*40 partials
    float* pairE = part + (size_t)KCH * 2 * HN;   // 512
    float* pairT = pairE + 512;                   // 512

    k_proj<<<dim3(NROWS / 16, KCH, 2), 256, 0, stream>>>(x, y, W1, part);
    k_red<<<(2 * HN) / 256, 256, 0, stream>>>(part, b1, hxb, hy);
    k_pair<<<dim3(NROWS / BI, NROWS / BJ), 512, 0, stream>>>(hxb, hy, W2, b2, pairE, pairT);
    k_fin<<<1, 512, 0, stream>>>(pairE, pairT, out);
}